// Round 1
// 1344.801 us; speedup vs baseline: 1.0201x; 1.0201x over previous
//
#include <hip/hip_runtime.h>
#include <cstdint>
#include <cstddef>

typedef __bf16 bf16;
typedef bf16  bf16x8 __attribute__((ext_vector_type(8)));
typedef bf16  bf16x4 __attribute__((ext_vector_type(4)));
typedef float floatx4 __attribute__((ext_vector_type(4)));

#define D_DIM 1024
#define E_NUM 16
#define F_DIM 4096
#define V_DIM 32000
#define T_TOK 2048
#define MAXPE 2048     // max tokens routed to one expert
#define SLOTS 6144     // max padded slots: 4096 + 16*127 rounded up
#define BM 128
#define BN 128
#define BK 32

// gemm_o grid: 250 col panels x 16 row blocks = 4000 blocks, 8 XCDs -> 500 per XCD
#define GO_BLOCKS 4000
#define GO_NXCD 8
#define GO_CPX (GO_BLOCKS / GO_NXCD)   // 500

// ---------------- async global->LDS (16B per lane, wave-uniform LDS base) --------------
__device__ __forceinline__ void async_ld16(const void* g, void* l) {
  __builtin_amdgcn_global_load_lds((__attribute__((address_space(1))) void*)g,
                                   (__attribute__((address_space(3))) void*)l,
                                   16, 0, 0);
}

struct __align__(16) GemmSmem {
  bf16 A[BM * BK];   // [m][k] row-major, 8 KB
  bf16 B[BN * BK];   // [n][k] row-major, 8 KB
};

// ---------------- shared 128x128 MFMA main loop (A:[M,K] bf16, BT:[N,K] bf16) ----------
// m97 structure: global_load_lds dwordx4 staging, ds_read_b128 fragments,
// 16x16x32 bf16 MFMA, wave grid 2x2, 4x4 fragments per wave.
__device__ __forceinline__ void gemm_mainloop(const bf16* __restrict__ Ag,  // at (m0,0)
                                              const bf16* __restrict__ Bg,  // at (n0,0)
                                              int K, int lda, int ldb,
                                              GemmSmem* sm, floatx4 acc[4][4]) {
  const int tid  = threadIdx.x;
  const int wave = tid >> 6;
  const int lane = tid & 63;
  const int q = lane >> 4;
  const int r = lane & 15;
  const int wm = (wave & 1) * 64;
  const int wn = (wave >> 1) * 64;

  // staging: 8 wave-instructions of 1KB each cover one 8KB tile.
  // byte offset within tile = row*64 + kc*16  (row-major [128][32] bf16)
  const int off0 = (wave * 2 + 0) * 1024 + lane * 16;
  const int off1 = (wave * 2 + 1) * 1024 + lane * 16;
  const int row0 = off0 >> 6, kc0 = (off0 >> 4) & 3;
  const int row1 = off1 >> 6, kc1 = (off1 >> 4) & 3;

  const bf16* a0 = Ag + (size_t)row0 * lda + kc0 * 8;
  const bf16* a1 = Ag + (size_t)row1 * lda + kc1 * 8;
  const bf16* b0 = Bg + (size_t)row0 * ldb + kc0 * 8;
  const bf16* b1 = Bg + (size_t)row1 * ldb + kc1 * 8;
  bf16* lA0 = sm->A + (wave * 2 + 0) * 512;
  bf16* lA1 = sm->A + (wave * 2 + 1) * 512;
  bf16* lB0 = sm->B + (wave * 2 + 0) * 512;
  bf16* lB1 = sm->B + (wave * 2 + 1) * 512;

  for (int k0 = 0; k0 < K; k0 += BK) {
    async_ld16(a0 + k0, lA0);
    async_ld16(a1 + k0, lA1);
    async_ld16(b0 + k0, lB0);
    async_ld16(b1 + k0, lB1);
    __syncthreads();  // drains vmcnt (staging complete) + barrier
    bf16x8 af[4], bfr[4];
#pragma unroll
    for (int i = 0; i < 4; ++i)
      af[i] = *(const bf16x8*)(sm->A + (wm + i * 16 + r) * BK + q * 8);
#pragma unroll
    for (int i = 0; i < 4; ++i)
      bfr[i] = *(const bf16x8*)(sm->B + (wn + i * 16 + r) * BK + q * 8);
#pragma unroll
    for (int mf = 0; mf < 4; ++mf)
#pragma unroll
      for (int nf = 0; nf < 4; ++nf)
        acc[mf][nf] = __builtin_amdgcn_mfma_f32_16x16x32_bf16(af[mf], bfr[nf], acc[mf][nf], 0, 0, 0);
    __syncthreads();  // all reads done before next stage overwrites LDS
  }
}

__device__ __forceinline__ void acc_zero(floatx4 acc[4][4]) {
#pragma unroll
  for (int a = 0; a < 4; ++a)
#pragma unroll
    for (int b = 0; b < 4; ++b) acc[a][b] = (floatx4){0.f, 0.f, 0.f, 0.f};
}

// ---------------- transpose + fp32->bf16 convert: src[K][N] -> dst[N][K] ----------------
__global__ __launch_bounds__(256) void k_transpose(const float* __restrict__ src,
                                                   bf16* __restrict__ dst, int K, int N,
                                                   size_t sstride, size_t dstride) {
  src += (size_t)blockIdx.z * sstride;
  dst += (size_t)blockIdx.z * dstride;
  const int n0 = blockIdx.x * 64, k0 = blockIdx.y * 64;
  __shared__ float t[64][65];
  const int tid = threadIdx.x;
  const int cr = tid >> 4;          // 0..15
  const int cc = (tid & 15) * 4;    // col group
#pragma unroll
  for (int p = 0; p < 4; ++p) {
    int row = p * 16 + cr;
    float4 v = *(const float4*)(src + (size_t)(k0 + row) * N + n0 + cc);
    t[row][cc] = v.x; t[row][cc + 1] = v.y; t[row][cc + 2] = v.z; t[row][cc + 3] = v.w;
  }
  __syncthreads();
  const int n = tid >> 2;           // 0..63
  const int kg = (tid & 3) * 16;
  bf16x8 o0, o1;
#pragma unroll
  for (int j = 0; j < 8; ++j) o0[j] = (bf16)t[kg + j][n];
#pragma unroll
  for (int j = 0; j < 8; ++j) o1[j] = (bf16)t[kg + 8 + j][n];
  bf16* dp = dst + (size_t)(n0 + n) * K + k0 + kg;
  *(bf16x8*)(dp) = o0;
  *(bf16x8*)(dp + 8) = o1;
}

// ---------------- gating: logits, top-2, softmax, routing lists -------------------------
__global__ __launch_bounds__(64) void k_gate(const int* __restrict__ x,
                                             const float* __restrict__ emb,
                                             const float* __restrict__ Wg,
                                             int* __restrict__ cnt, int* __restrict__ atok,
                                             float* __restrict__ aw) {
  const int t = blockIdx.x;
  const int lane = threadIdx.x;
  const int xid = x[t];
  const float* h = emb + (size_t)xid * D_DIM;
  float le[E_NUM];
#pragma unroll
  for (int e = 0; e < E_NUM; ++e) le[e] = 0.f;
  for (int i = 0; i < D_DIM / 64; ++i) {
    int d = i * 64 + lane;
    float hv = h[d];
    const float* wr = Wg + (size_t)d * E_NUM;
#pragma unroll
    for (int e = 0; e < E_NUM; ++e) le[e] += hv * wr[e];
  }
#pragma unroll
  for (int off = 32; off > 0; off >>= 1)
#pragma unroll
    for (int e = 0; e < E_NUM; ++e) le[e] += __shfl_xor(le[e], off);
  if (lane == 0) {
    int i0 = 0; float v0 = le[0];
#pragma unroll
    for (int e = 1; e < E_NUM; ++e) if (le[e] > v0) { v0 = le[e]; i0 = e; }
    int i1 = -1; float v1 = -1e30f;
#pragma unroll
    for (int e = 0; e < E_NUM; ++e) if (e != i0 && le[e] > v1) { v1 = le[e]; i1 = e; }
    float e1 = __expf(v1 - v0);
    float inv = 1.f / (1.f + e1);
    int p0 = atomicAdd(&cnt[i0], 1);
    atok[i0 * MAXPE + p0] = t; aw[i0 * MAXPE + p0] = inv;
    int p1 = atomicAdd(&cnt[i1], 1);
    atok[i1 * MAXPE + p1] = t; aw[i1 * MAXPE + p1] = e1 * inv;
  }
}

// ---------------- padded prefix offsets (tiny) ------------------------------------------
__global__ void k_offs(const int* __restrict__ cnt, int* __restrict__ offs) {
  if (threadIdx.x == 0) {
    int a = 0; offs[0] = 0;
    for (int e = 0; e < E_NUM; ++e) { a += (cnt[e] + BM - 1) & ~(BM - 1); offs[e + 1] = a; }
  }
}

// ---------------- gather token embeddings into per-expert compact bf16 A ---------------
__global__ __launch_bounds__(256) void k_gather(const int* __restrict__ x,
                                                const float* __restrict__ emb,
                                                const int* __restrict__ atok,
                                                const float* __restrict__ aw,
                                                const int* __restrict__ offs,
                                                const int* __restrict__ cnt,
                                                bf16* __restrict__ Ag,
                                                int* __restrict__ stok,
                                                float* __restrict__ sw) {
  const int e = blockIdx.x, c = blockIdx.y;
  const int base = offs[e];
  const int padcnt = offs[e + 1] - base;
  if (c * BM >= padcnt) return;
  const int cn = cnt[e];
  const int tid = threadIdx.x;
  for (int rl = 0; rl < BM; ++rl) {
    int lr = c * BM + rl;
    int slot = base + lr;
    bf16* dst = Ag + (size_t)slot * D_DIM + tid * 4;
    if (lr < cn) {
      int tok = atok[e * MAXPE + lr];
      if (tid == 0) { stok[slot] = tok; sw[slot] = aw[e * MAXPE + lr]; }
      int xid = x[tok];
      float4 v = *(const float4*)(emb + (size_t)xid * D_DIM + tid * 4);
      bf16x4 o; o[0] = (bf16)v.x; o[1] = (bf16)v.y; o[2] = (bf16)v.z; o[3] = (bf16)v.w;
      *(bf16x4*)dst = o;
    } else {
      if (tid == 0) { stok[slot] = 0; sw[slot] = 0.f; }
      bf16x4 z; z[0] = (bf16)0.f; z[1] = (bf16)0.f; z[2] = (bf16)0.f; z[3] = (bf16)0.f;
      *(bf16x4*)dst = z;
    }
  }
}

// ---------------- GEMM1: H = relu(A @ W1[e] + b1[e]), per-expert ------------------------
__global__ __launch_bounds__(256, 2) void k_gemm1(const bf16* __restrict__ Ag,
                                                  const bf16* __restrict__ W1T,
                                                  const float* __restrict__ b1,
                                                  bf16* __restrict__ H,
                                                  const int* __restrict__ offs) {
  const int e = blockIdx.z;
  const int base = offs[e];
  const int padcnt = offs[e + 1] - base;
  const int m0 = blockIdx.y * BM;
  if (m0 >= padcnt) return;
  const int n0 = blockIdx.x * BN;
  __shared__ GemmSmem sm;
  floatx4 acc[4][4];
  acc_zero(acc);
  gemm_mainloop(Ag + (size_t)(base + m0) * D_DIM,
                W1T + (size_t)e * F_DIM * D_DIM + (size_t)n0 * D_DIM,
                D_DIM, D_DIM, D_DIM, &sm, acc);
  const int tid = threadIdx.x, wave = tid >> 6, lane = tid & 63;
  const int q = lane >> 4, r = lane & 15;
  const int wm = (wave & 1) * 64, wn = (wave >> 1) * 64;
  const float* b1e = b1 + (size_t)e * F_DIM;
#pragma unroll
  for (int nf = 0; nf < 4; ++nf) {
    int col = n0 + wn + nf * 16 + r;
    float bb = b1e[col];
#pragma unroll
    for (int mf = 0; mf < 4; ++mf)
#pragma unroll
      for (int i = 0; i < 4; ++i) {
        int rowl = m0 + wm + mf * 16 + q * 4 + i;
        float v = acc[mf][nf][i] + bb;
        v = v > 0.f ? v : 0.f;
        H[(size_t)(base + rowl) * F_DIM + col] = (bf16)v;
      }
  }
}

// ---------------- GEMM2: y[tok] += w_slot * (H @ W2[e] + b2[e]) -------------------------
__global__ __launch_bounds__(256, 2) void k_gemm2(const bf16* __restrict__ H,
                                                  const bf16* __restrict__ W2T,
                                                  const float* __restrict__ b2,
                                                  float* __restrict__ y,
                                                  const int* __restrict__ offs,
                                                  const int* __restrict__ cnt,
                                                  const int* __restrict__ stok,
                                                  const float* __restrict__ sw) {
  const int e = blockIdx.z;
  const int base = offs[e];
  const int padcnt = offs[e + 1] - base;
  const int m0 = blockIdx.y * BM;
  if (m0 >= padcnt) return;
  const int n0 = blockIdx.x * BN;
  __shared__ GemmSmem sm;
  floatx4 acc[4][4];
  acc_zero(acc);
  gemm_mainloop(H + (size_t)(base + m0) * F_DIM,
                W2T + (size_t)e * D_DIM * F_DIM + (size_t)n0 * F_DIM,
                F_DIM, F_DIM, F_DIM, &sm, acc);
  const int tid = threadIdx.x, wave = tid >> 6, lane = tid & 63;
  const int q = lane >> 4, r = lane & 15;
  const int wm = (wave & 1) * 64, wn = (wave >> 1) * 64;
  const int cn = cnt[e];
  const float* b2e = b2 + (size_t)e * D_DIM;
#pragma unroll
  for (int nf = 0; nf < 4; ++nf) {
    int col = n0 + wn + nf * 16 + r;
    float bb = b2e[col];
#pragma unroll
    for (int mf = 0; mf < 4; ++mf)
#pragma unroll
      for (int i = 0; i < 4; ++i) {
        int rowl = m0 + wm + mf * 16 + q * 4 + i;
        if (rowl < cn) {
          int slot = base + rowl;
          float v = (acc[mf][nf][i] + bb) * sw[slot];
          atomicAdd(y + (size_t)stok[slot] * D_DIM + col, v);
        }
      }
  }
}

// ---------------- y fp32 -> bf16 --------------------------------------------------------
__global__ __launch_bounds__(256) void k_cvty(const float* __restrict__ y,
                                              bf16* __restrict__ yb) {
  const int i = (blockIdx.x * 256 + threadIdx.x) * 4;
  float4 v = *(const float4*)(y + i);
  bf16x4 o; o[0] = (bf16)v.x; o[1] = (bf16)v.y; o[2] = (bf16)v.z; o[3] = (bf16)v.w;
  *(bf16x4*)(yb + i) = o;
}

// ---------------- final projection: out = y @ Wo + bo -----------------------------------
// 1-D grid of GO_BLOCKS; XCD-chunked swizzle so that all 16 row-blocks of a WoT
// column panel run consecutively on the SAME XCD (panel fetched from HBM once).
// Default mapping had same-panel blocks 250 apart (250%8=2 -> different XCDs ->
// each XCD refetched the whole 65.5 MB WoT: measured FETCH 607 MB ~= 8x65.5 + yb).
__global__ __launch_bounds__(256, 2) void k_gemm_o(const bf16* __restrict__ yb,
                                                   const bf16* __restrict__ WoT,
                                                   const float* __restrict__ bo,
                                                   float* __restrict__ out) {
  const int lin = blockIdx.x;                    // 0..3999, XCD = lin % 8
  const int swz = (lin & 7) * GO_CPX + (lin >> 3);
  const int m0 = (swz & 15) * BM;                // row block fastest within a panel
  const int n0 = (swz >> 4) * BN;                // 250 column panels
  __shared__ GemmSmem sm;
  floatx4 acc[4][4];
  acc_zero(acc);
  gemm_mainloop(yb + (size_t)m0 * D_DIM, WoT + (size_t)n0 * D_DIM,
                D_DIM, D_DIM, D_DIM, &sm, acc);
  const int tid = threadIdx.x, wave = tid >> 6, lane = tid & 63;
  const int q = lane >> 4, r = lane & 15;
  const int wm = (wave & 1) * 64, wn = (wave >> 1) * 64;
#pragma unroll
  for (int nf = 0; nf < 4; ++nf) {
    int col = n0 + wn + nf * 16 + r;
    float bb = bo[col];
#pragma unroll
    for (int mf = 0; mf < 4; ++mf)
#pragma unroll
      for (int i = 0; i < 4; ++i) {
        int row = m0 + wm + mf * 16 + q * 4 + i;
        out[(size_t)row * V_DIM + col] = acc[mf][nf][i] + bb;
      }
  }
}

// ---------------- launch ----------------------------------------------------------------
extern "C" void kernel_launch(void* const* d_in, const int* in_sizes, int n_in,
                              void* d_out, int out_size, void* d_ws, size_t ws_size,
                              hipStream_t stream) {
  const int*   x   = (const int*)d_in[0];
  const float* emb = (const float*)d_in[1];
  const float* Wg  = (const float*)d_in[2];
  const float* W1  = (const float*)d_in[3];
  const float* b1  = (const float*)d_in[4];
  const float* W2  = (const float*)d_in[5];
  const float* b2  = (const float*)d_in[6];
  const float* Wo  = (const float*)d_in[7];
  const float* bo  = (const float*)d_in[8];
  float* out = (float*)d_out;

  char* p = (char*)d_ws;
  bf16*  W1T  = (bf16*)p;  p += (size_t)E_NUM * F_DIM * D_DIM * 2;   // 134.2 MB
  bf16*  W2T  = (bf16*)p;  p += (size_t)E_NUM * D_DIM * F_DIM * 2;   // 134.2 MB
  bf16*  WoT  = (bf16*)p;  p += (size_t)V_DIM * D_DIM * 2;           //  65.5 MB
  bf16*  Ag   = (bf16*)p;  p += (size_t)SLOTS * D_DIM * 2;           //  12.6 MB
  bf16*  H    = (bf16*)p;  p += (size_t)SLOTS * F_DIM * 2;           //  50.3 MB
  float* y    = (float*)p; p += (size_t)T_TOK * D_DIM * 4;           //   8.4 MB
  bf16*  yb   = (bf16*)p;  p += (size_t)T_TOK * D_DIM * 2;           //   4.2 MB
  int*   cnt  = (int*)p;   p += 256;
  int*   offs = (int*)p;   p += 256;
  int*   atok = (int*)p;   p += (size_t)E_NUM * MAXPE * 4;
  float* aw   = (float*)p; p += (size_t)E_NUM * MAXPE * 4;
  int*   stok = (int*)p;   p += SLOTS * 4;
  float* sw   = (float*)p; p += SLOTS * 4;
  if ((size_t)(p - (char*)d_ws) > ws_size) return;  // ws too small: bail (fails loudly)

  hipMemsetAsync(cnt, 0, 64, stream);
  hipMemsetAsync(y, 0, (size_t)T_TOK * D_DIM * 4, stream);

  // transposes: src[K][N] -> dst[N][K] bf16
  k_transpose<<<dim3(F_DIM / 64, D_DIM / 64, E_NUM), 256, 0, stream>>>(
      W1, W1T, D_DIM, F_DIM, (size_t)D_DIM * F_DIM, (size_t)F_DIM * D_DIM);
  k_transpose<<<dim3(D_DIM / 64, F_DIM / 64, E_NUM), 256, 0, stream>>>(
      W2, W2T, F_DIM, D_DIM, (size_t)F_DIM * D_DIM, (size_t)D_DIM * F_DIM);
  k_transpose<<<dim3(V_DIM / 64, D_DIM / 64, 1), 256, 0, stream>>>(
      Wo, WoT, D_DIM, V_DIM, 0, 0);

  k_gate<<<T_TOK, 64, 0, stream>>>(x, emb, Wg, cnt, atok, aw);
  k_offs<<<1, 64, 0, stream>>>(cnt, offs);
  k_gather<<<dim3(E_NUM, T_TOK / BM), 256, 0, stream>>>(x, emb, atok, aw, offs, cnt, Ag, stok, sw);

  k_gemm1<<<dim3(F_DIM / BN, T_TOK / BM, E_NUM), 256, 0, stream>>>(Ag, W1T, b1, H, offs);
  k_gemm2<<<dim3(D_DIM / BN, T_TOK / BM, E_NUM), 256, 0, stream>>>(H, W2T, b2, y, offs, cnt, stok, sw);
  k_cvty<<<(T_TOK * D_DIM) / 1024, 256, 0, stream>>>(y, yb);
  k_gemm_o<<<dim3(GO_BLOCKS), 256, 0, stream>>>(yb, WoT, bo, out);
}

// Round 2
// 1267.746 us; speedup vs baseline: 1.0821x; 1.0608x over previous
//
#include <hip/hip_runtime.h>
#include <cstdint>
#include <cstddef>

typedef __bf16 bf16;
typedef bf16  bf16x8 __attribute__((ext_vector_type(8)));
typedef bf16  bf16x4 __attribute__((ext_vector_type(4)));
typedef float floatx4 __attribute__((ext_vector_type(4)));

#define D_DIM 1024
#define E_NUM 16
#define F_DIM 4096
#define V_DIM 32000
#define T_TOK 2048
#define MAXPE 2048     // max tokens routed to one expert
#define SLOTS 6144     // max padded slots: 4096 + 16*127 rounded up
#define BM 128
#define BN 128
#define BK 32

// gemm_o grid: 250 col panels x 16 row blocks = 4000 blocks, 8 XCDs -> 500 per XCD
#define GO_BLOCKS 4000
#define GO_NXCD 8
#define GO_CPX (GO_BLOCKS / GO_NXCD)   // 500

// gemm2 split-K: K=4096 -> 4 chunks of 1024. Static grid 8 panels x 16 rows x 16 e x 4 ks
#define G2_KS 4
#define G2_KCHUNK (F_DIM / G2_KS)          // 1024
#define G2_BLOCKS (8 * 16 * E_NUM * G2_KS) // 8192
#define G2_CPX (G2_BLOCKS / 8)             // 1024 per XCD

// ---------------- async global->LDS (16B per lane, wave-uniform LDS base) --------------
__device__ __forceinline__ void async_ld16(const void* g, void* l) {
  __builtin_amdgcn_global_load_lds((__attribute__((address_space(1))) void*)g,
                                   (__attribute__((address_space(3))) void*)l,
                                   16, 0, 0);
}

struct __align__(16) GemmSmem {
  bf16 A[BM * BK];   // [m][k] row-major, 8 KB
  bf16 B[BN * BK];   // [n][k] row-major, 8 KB
};

// ---------------- shared 128x128 MFMA main loop (A:[M,K] bf16, BT:[N,K] bf16) ----------
// m97 structure: global_load_lds dwordx4 staging, ds_read_b128 fragments,
// 16x16x32 bf16 MFMA, wave grid 2x2, 4x4 fragments per wave.
__device__ __forceinline__ void gemm_mainloop(const bf16* __restrict__ Ag,  // at (m0,0)
                                              const bf16* __restrict__ Bg,  // at (n0,0)
                                              int K, int lda, int ldb,
                                              GemmSmem* sm, floatx4 acc[4][4]) {
  const int tid  = threadIdx.x;
  const int wave = tid >> 6;
  const int lane = tid & 63;
  const int q = lane >> 4;
  const int r = lane & 15;
  const int wm = (wave & 1) * 64;
  const int wn = (wave >> 1) * 64;

  // staging: 8 wave-instructions of 1KB each cover one 8KB tile.
  // byte offset within tile = row*64 + kc*16  (row-major [128][32] bf16)
  const int off0 = (wave * 2 + 0) * 1024 + lane * 16;
  const int off1 = (wave * 2 + 1) * 1024 + lane * 16;
  const int row0 = off0 >> 6, kc0 = (off0 >> 4) & 3;
  const int row1 = off1 >> 6, kc1 = (off1 >> 4) & 3;

  const bf16* a0 = Ag + (size_t)row0 * lda + kc0 * 8;
  const bf16* a1 = Ag + (size_t)row1 * lda + kc1 * 8;
  const bf16* b0 = Bg + (size_t)row0 * ldb + kc0 * 8;
  const bf16* b1 = Bg + (size_t)row1 * ldb + kc1 * 8;
  bf16* lA0 = sm->A + (wave * 2 + 0) * 512;
  bf16* lA1 = sm->A + (wave * 2 + 1) * 512;
  bf16* lB0 = sm->B + (wave * 2 + 0) * 512;
  bf16* lB1 = sm->B + (wave * 2 + 1) * 512;

  for (int k0 = 0; k0 < K; k0 += BK) {
    async_ld16(a0 + k0, lA0);
    async_ld16(a1 + k0, lA1);
    async_ld16(b0 + k0, lB0);
    async_ld16(b1 + k0, lB1);
    __syncthreads();  // drains vmcnt (staging complete) + barrier
    bf16x8 af[4], bfr[4];
#pragma unroll
    for (int i = 0; i < 4; ++i)
      af[i] = *(const bf16x8*)(sm->A + (wm + i * 16 + r) * BK + q * 8);
#pragma unroll
    for (int i = 0; i < 4; ++i)
      bfr[i] = *(const bf16x8*)(sm->B + (wn + i * 16 + r) * BK + q * 8);
#pragma unroll
    for (int mf = 0; mf < 4; ++mf)
#pragma unroll
      for (int nf = 0; nf < 4; ++nf)
        acc[mf][nf] = __builtin_amdgcn_mfma_f32_16x16x32_bf16(af[mf], bfr[nf], acc[mf][nf], 0, 0, 0);
    __syncthreads();  // all reads done before next stage overwrites LDS
  }
}

__device__ __forceinline__ void acc_zero(floatx4 acc[4][4]) {
#pragma unroll
  for (int a = 0; a < 4; ++a)
#pragma unroll
    for (int b = 0; b < 4; ++b) acc[a][b] = (floatx4){0.f, 0.f, 0.f, 0.f};
}

// ---------------- transpose + fp32->bf16 convert: src[K][N] -> dst[N][K] ----------------
__global__ __launch_bounds__(256) void k_transpose(const float* __restrict__ src,
                                                   bf16* __restrict__ dst, int K, int N,
                                                   size_t sstride, size_t dstride) {
  src += (size_t)blockIdx.z * sstride;
  dst += (size_t)blockIdx.z * dstride;
  const int n0 = blockIdx.x * 64, k0 = blockIdx.y * 64;
  __shared__ float t[64][65];
  const int tid = threadIdx.x;
  const int cr = tid >> 4;          // 0..15
  const int cc = (tid & 15) * 4;    // col group
#pragma unroll
  for (int p = 0; p < 4; ++p) {
    int row = p * 16 + cr;
    float4 v = *(const float4*)(src + (size_t)(k0 + row) * N + n0 + cc);
    t[row][cc] = v.x; t[row][cc + 1] = v.y; t[row][cc + 2] = v.z; t[row][cc + 3] = v.w;
  }
  __syncthreads();
  const int n = tid >> 2;           // 0..63
  const int kg = (tid & 3) * 16;
  bf16x8 o0, o1;
#pragma unroll
  for (int j = 0; j < 8; ++j) o0[j] = (bf16)t[kg + j][n];
#pragma unroll
  for (int j = 0; j < 8; ++j) o1[j] = (bf16)t[kg + 8 + j][n];
  bf16* dp = dst + (size_t)(n0 + n) * K + k0 + kg;
  *(bf16x8*)(dp) = o0;
  *(bf16x8*)(dp + 8) = o1;
}

// ---------------- gating: logits, top-2, softmax, routing lists -------------------------
__global__ __launch_bounds__(64) void k_gate(const int* __restrict__ x,
                                             const float* __restrict__ emb,
                                             const float* __restrict__ Wg,
                                             int* __restrict__ cnt, int* __restrict__ atok,
                                             float* __restrict__ aw) {
  const int t = blockIdx.x;
  const int lane = threadIdx.x;
  const int xid = x[t];
  const float* h = emb + (size_t)xid * D_DIM;
  float le[E_NUM];
#pragma unroll
  for (int e = 0; e < E_NUM; ++e) le[e] = 0.f;
  for (int i = 0; i < D_DIM / 64; ++i) {
    int d = i * 64 + lane;
    float hv = h[d];
    const float* wr = Wg + (size_t)d * E_NUM;
#pragma unroll
    for (int e = 0; e < E_NUM; ++e) le[e] += hv * wr[e];
  }
#pragma unroll
  for (int off = 32; off > 0; off >>= 1)
#pragma unroll
    for (int e = 0; e < E_NUM; ++e) le[e] += __shfl_xor(le[e], off);
  if (lane == 0) {
    int i0 = 0; float v0 = le[0];
#pragma unroll
    for (int e = 1; e < E_NUM; ++e) if (le[e] > v0) { v0 = le[e]; i0 = e; }
    int i1 = -1; float v1 = -1e30f;
#pragma unroll
    for (int e = 0; e < E_NUM; ++e) if (e != i0 && le[e] > v1) { v1 = le[e]; i1 = e; }
    float e1 = __expf(v1 - v0);
    float inv = 1.f / (1.f + e1);
    int p0 = atomicAdd(&cnt[i0], 1);
    atok[i0 * MAXPE + p0] = t; aw[i0 * MAXPE + p0] = inv;
    int p1 = atomicAdd(&cnt[i1], 1);
    atok[i1 * MAXPE + p1] = t; aw[i1 * MAXPE + p1] = e1 * inv;
  }
}

// ---------------- padded prefix offsets (tiny) ------------------------------------------
__global__ void k_offs(const int* __restrict__ cnt, int* __restrict__ offs) {
  if (threadIdx.x == 0) {
    int a = 0; offs[0] = 0;
    for (int e = 0; e < E_NUM; ++e) { a += (cnt[e] + BM - 1) & ~(BM - 1); offs[e + 1] = a; }
  }
}

// ---------------- gather token embeddings into per-expert compact bf16 A ---------------
__global__ __launch_bounds__(256) void k_gather(const int* __restrict__ x,
                                                const float* __restrict__ emb,
                                                const int* __restrict__ atok,
                                                const float* __restrict__ aw,
                                                const int* __restrict__ offs,
                                                const int* __restrict__ cnt,
                                                bf16* __restrict__ Ag,
                                                int* __restrict__ stok,
                                                float* __restrict__ sw) {
  const int e = blockIdx.x, c = blockIdx.y;
  const int base = offs[e];
  const int padcnt = offs[e + 1] - base;
  if (c * BM >= padcnt) return;
  const int cn = cnt[e];
  const int tid = threadIdx.x;
  for (int rl = 0; rl < BM; ++rl) {
    int lr = c * BM + rl;
    int slot = base + lr;
    bf16* dst = Ag + (size_t)slot * D_DIM + tid * 4;
    if (lr < cn) {
      int tok = atok[e * MAXPE + lr];
      if (tid == 0) { stok[slot] = tok; sw[slot] = aw[e * MAXPE + lr]; }
      int xid = x[tok];
      float4 v = *(const float4*)(emb + (size_t)xid * D_DIM + tid * 4);
      bf16x4 o; o[0] = (bf16)v.x; o[1] = (bf16)v.y; o[2] = (bf16)v.z; o[3] = (bf16)v.w;
      *(bf16x4*)dst = o;
    } else {
      if (tid == 0) { stok[slot] = 0; sw[slot] = 0.f; }
      bf16x4 z; z[0] = (bf16)0.f; z[1] = (bf16)0.f; z[2] = (bf16)0.f; z[3] = (bf16)0.f;
      *(bf16x4*)dst = z;
    }
  }
}

// ---------------- GEMM1: H = relu(A @ W1[e] + b1[e]), per-expert ------------------------
__global__ __launch_bounds__(256, 2) void k_gemm1(const bf16* __restrict__ Ag,
                                                  const bf16* __restrict__ W1T,
                                                  const float* __restrict__ b1,
                                                  bf16* __restrict__ H,
                                                  const int* __restrict__ offs) {
  const int e = blockIdx.z;
  const int base = offs[e];
  const int padcnt = offs[e + 1] - base;
  const int m0 = blockIdx.y * BM;
  if (m0 >= padcnt) return;
  const int n0 = blockIdx.x * BN;
  __shared__ GemmSmem sm;
  floatx4 acc[4][4];
  acc_zero(acc);
  gemm_mainloop(Ag + (size_t)(base + m0) * D_DIM,
                W1T + (size_t)e * F_DIM * D_DIM + (size_t)n0 * D_DIM,
                D_DIM, D_DIM, D_DIM, &sm, acc);
  const int tid = threadIdx.x, wave = tid >> 6, lane = tid & 63;
  const int q = lane >> 4, r = lane & 15;
  const int wm = (wave & 1) * 64, wn = (wave >> 1) * 64;
  const float* b1e = b1 + (size_t)e * F_DIM;
#pragma unroll
  for (int nf = 0; nf < 4; ++nf) {
    int col = n0 + wn + nf * 16 + r;
    float bb = b1e[col];
#pragma unroll
    for (int mf = 0; mf < 4; ++mf)
#pragma unroll
      for (int i = 0; i < 4; ++i) {
        int rowl = m0 + wm + mf * 16 + q * 4 + i;
        float v = acc[mf][nf][i] + bb;
        v = v > 0.f ? v : 0.f;
        H[(size_t)(base + rowl) * F_DIM + col] = (bf16)v;
      }
  }
}

// ---------------- GEMM2 (split-K): y[tok] += w_slot * (H @ W2[e] + b2[e]) ---------------
// Round-1 counters: 256 active blocks (1/CU), MfmaUtil 8%, Occupancy 11% -> latency-bound.
// Split K=4096 into 4 chunks (atomicAdd into fp32 y is already the accumulator; bias
// added only by the ks==0 slice). Static grid 8192 blocks, chunk-swizzled so each
// (e,ks) group (H-chunk 0.5 MB + W2T-chunk 2 MB < 4 MB L2) lands on ONE XCD.
__global__ __launch_bounds__(256, 2) void k_gemm2(const bf16* __restrict__ H,
                                                  const bf16* __restrict__ W2T,
                                                  const float* __restrict__ b2,
                                                  float* __restrict__ y,
                                                  const int* __restrict__ offs,
                                                  const int* __restrict__ cnt,
                                                  const int* __restrict__ stok,
                                                  const float* __restrict__ sw) {
  const int lin = blockIdx.x;                       // 0..8191, XCD = lin % 8
  const int swz = (lin & 7) * G2_CPX + (lin >> 3);  // contiguous 1024-range per XCD
  const int g     = swz >> 7;                       // 0..63 group = (ks, e)
  const int inner = swz & 127;                      // 0..127 within group
  const int ks = g >> 4;                            // 0..3 K-slice
  const int e  = g & 15;                            // expert
  const int m0 = (inner >> 3) * BM;                 // row block 0..15 (mostly inactive)
  const int n0 = (inner & 7) * BN;                  // col panel fastest -> actives contiguous
  const int base = offs[e];
  const int padcnt = offs[e + 1] - base;
  if (m0 >= padcnt) return;
  __shared__ GemmSmem sm;
  floatx4 acc[4][4];
  acc_zero(acc);
  gemm_mainloop(H + (size_t)(base + m0) * F_DIM + ks * G2_KCHUNK,
                W2T + (size_t)e * D_DIM * F_DIM + (size_t)n0 * F_DIM + ks * G2_KCHUNK,
                G2_KCHUNK, F_DIM, F_DIM, &sm, acc);
  const int tid = threadIdx.x, wave = tid >> 6, lane = tid & 63;
  const int q = lane >> 4, r = lane & 15;
  const int wm = (wave & 1) * 64, wn = (wave >> 1) * 64;
  const int cn = cnt[e];
  const float* b2e = b2 + (size_t)e * D_DIM;
#pragma unroll
  for (int nf = 0; nf < 4; ++nf) {
    int col = n0 + wn + nf * 16 + r;
    float bb = (ks == 0) ? b2e[col] : 0.f;
#pragma unroll
    for (int mf = 0; mf < 4; ++mf)
#pragma unroll
      for (int i = 0; i < 4; ++i) {
        int rowl = m0 + wm + mf * 16 + q * 4 + i;
        if (rowl < cn) {
          int slot = base + rowl;
          float v = (acc[mf][nf][i] + bb) * sw[slot];
          atomicAdd(y + (size_t)stok[slot] * D_DIM + col, v);
        }
      }
  }
}

// ---------------- y fp32 -> bf16 --------------------------------------------------------
__global__ __launch_bounds__(256) void k_cvty(const float* __restrict__ y,
                                              bf16* __restrict__ yb) {
  const int i = (blockIdx.x * 256 + threadIdx.x) * 4;
  float4 v = *(const float4*)(y + i);
  bf16x4 o; o[0] = (bf16)v.x; o[1] = (bf16)v.y; o[2] = (bf16)v.z; o[3] = (bf16)v.w;
  *(bf16x4*)(yb + i) = o;
}

// ---------------- final projection: out = y @ Wo + bo -----------------------------------
// 1-D grid of GO_BLOCKS; XCD-chunked swizzle so that all 16 row-blocks of a WoT
// column panel run consecutively on the SAME XCD (panel fetched from HBM once).
__global__ __launch_bounds__(256, 2) void k_gemm_o(const bf16* __restrict__ yb,
                                                   const bf16* __restrict__ WoT,
                                                   const float* __restrict__ bo,
                                                   float* __restrict__ out) {
  const int lin = blockIdx.x;                    // 0..3999, XCD = lin % 8
  const int swz = (lin & 7) * GO_CPX + (lin >> 3);
  const int m0 = (swz & 15) * BM;                // row block fastest within a panel
  const int n0 = (swz >> 4) * BN;                // 250 column panels
  __shared__ GemmSmem sm;
  floatx4 acc[4][4];
  acc_zero(acc);
  gemm_mainloop(yb + (size_t)m0 * D_DIM, WoT + (size_t)n0 * D_DIM,
                D_DIM, D_DIM, D_DIM, &sm, acc);
  const int tid = threadIdx.x, wave = tid >> 6, lane = tid & 63;
  const int q = lane >> 4, r = lane & 15;
  const int wm = (wave & 1) * 64, wn = (wave >> 1) * 64;
#pragma unroll
  for (int nf = 0; nf < 4; ++nf) {
    int col = n0 + wn + nf * 16 + r;
    float bb = bo[col];
#pragma unroll
    for (int mf = 0; mf < 4; ++mf)
#pragma unroll
      for (int i = 0; i < 4; ++i) {
        int row = m0 + wm + mf * 16 + q * 4 + i;
        out[(size_t)row * V_DIM + col] = acc[mf][nf][i] + bb;
      }
  }
}

// ---------------- launch ----------------------------------------------------------------
extern "C" void kernel_launch(void* const* d_in, const int* in_sizes, int n_in,
                              void* d_out, int out_size, void* d_ws, size_t ws_size,
                              hipStream_t stream) {
  const int*   x   = (const int*)d_in[0];
  const float* emb = (const float*)d_in[1];
  const float* Wg  = (const float*)d_in[2];
  const float* W1  = (const float*)d_in[3];
  const float* b1  = (const float*)d_in[4];
  const float* W2  = (const float*)d_in[5];
  const float* b2  = (const float*)d_in[6];
  const float* Wo  = (const float*)d_in[7];
  const float* bo  = (const float*)d_in[8];
  float* out = (float*)d_out;

  char* p = (char*)d_ws;
  bf16*  W1T  = (bf16*)p;  p += (size_t)E_NUM * F_DIM * D_DIM * 2;   // 134.2 MB
  bf16*  W2T  = (bf16*)p;  p += (size_t)E_NUM * D_DIM * F_DIM * 2;   // 134.2 MB
  bf16*  WoT  = (bf16*)p;  p += (size_t)V_DIM * D_DIM * 2;           //  65.5 MB
  bf16*  Ag   = (bf16*)p;  p += (size_t)SLOTS * D_DIM * 2;           //  12.6 MB
  bf16*  H    = (bf16*)p;  p += (size_t)SLOTS * F_DIM * 2;           //  50.3 MB
  float* y    = (float*)p; p += (size_t)T_TOK * D_DIM * 4;           //   8.4 MB
  bf16*  yb   = (bf16*)p;  p += (size_t)T_TOK * D_DIM * 2;           //   4.2 MB
  int*   cnt  = (int*)p;   p += 256;
  int*   offs = (int*)p;   p += 256;
  int*   atok = (int*)p;   p += (size_t)E_NUM * MAXPE * 4;
  float* aw   = (float*)p; p += (size_t)E_NUM * MAXPE * 4;
  int*   stok = (int*)p;   p += SLOTS * 4;
  float* sw   = (float*)p; p += SLOTS * 4;
  if ((size_t)(p - (char*)d_ws) > ws_size) return;  // ws too small: bail (fails loudly)

  hipMemsetAsync(cnt, 0, 64, stream);
  hipMemsetAsync(y, 0, (size_t)T_TOK * D_DIM * 4, stream);

  // transposes: src[K][N] -> dst[N][K] bf16
  k_transpose<<<dim3(F_DIM / 64, D_DIM / 64, E_NUM), 256, 0, stream>>>(
      W1, W1T, D_DIM, F_DIM, (size_t)D_DIM * F_DIM, (size_t)F_DIM * D_DIM);
  k_transpose<<<dim3(D_DIM / 64, F_DIM / 64, E_NUM), 256, 0, stream>>>(
      W2, W2T, F_DIM, D_DIM, (size_t)F_DIM * D_DIM, (size_t)D_DIM * F_DIM);
  k_transpose<<<dim3(V_DIM / 64, D_DIM / 64, 1), 256, 0, stream>>>(
      Wo, WoT, D_DIM, V_DIM, 0, 0);

  k_gate<<<T_TOK, 64, 0, stream>>>(x, emb, Wg, cnt, atok, aw);
  k_offs<<<1, 64, 0, stream>>>(cnt, offs);
  k_gather<<<dim3(E_NUM, T_TOK / BM), 256, 0, stream>>>(x, emb, atok, aw, offs, cnt, Ag, stok, sw);

  k_gemm1<<<dim3(F_DIM / BN, T_TOK / BM, E_NUM), 256, 0, stream>>>(Ag, W1T, b1, H, offs);
  k_gemm2<<<dim3(G2_BLOCKS), 256, 0, stream>>>(H, W2T, b2, y, offs, cnt, stok, sw);
  k_cvty<<<(T_TOK * D_DIM) / 1024, 256, 0, stream>>>(y, yb);
  k_gemm_o<<<dim3(GO_BLOCKS), 256, 0, stream>>>(yb, WoT, bo, out);
}